// Round 18
// baseline (158.865 us; speedup 1.0000x reference)
//
#include <hip/hip_runtime.h>
#include <stdint.h>

#define SS 64
#define NN 4096
#define FF 32
#define HH 64
#define OO 2
#define G3 192

typedef float f32x4 __attribute__((ext_vector_type(4)));
typedef short bf16x8 __attribute__((ext_vector_type(8)));
typedef unsigned short u16x8 __attribute__((ext_vector_type(8)));
typedef long longx2 __attribute__((ext_vector_type(2)));

#define AS1 __attribute__((address_space(1)))
#define AS3 __attribute__((address_space(3)))

__device__ __forceinline__ unsigned short f2bf(float f) {
  union { float f; uint32_t u; } v; v.f = f;
  uint32_t u = v.u;
  uint32_t r = (u + 0x7FFFu + ((u >> 16) & 1u)) >> 16;
  return (unsigned short)r;
}
__device__ __forceinline__ float bf2f(unsigned short s) {
  union { uint32_t u; float f; } v; v.u = ((uint32_t)s) << 16;
  return v.f;
}
// f32 -> OCP e4m3fn, RNE
__device__ __forceinline__ unsigned char f2e4m3(float x) {
  float a = fabsf(x);
  unsigned s = (x < 0.f) ? 0x80u : 0u;
  if (a >= 448.f) return (unsigned char)(s | 0x7E);
  if (a < 0.015625f) {
    int q = (int)rintf(a * 512.f);
    return (unsigned char)(s | (unsigned)q);
  }
  union { float f; uint32_t u; } v; v.f = a;
  uint32_t b = v.u + 0x7FFFFu + ((v.u >> 20) & 1u);
  int e = (int)(b >> 23) - 127;
  if (e > 8) return (unsigned char)(s | 0x7E);
  return (unsigned char)(s | (unsigned)(((e + 7) << 3) | ((b >> 20) & 7u)));
}
// k-permutation within a 128B group: 8B block b (0..15) -> ((b&7)<<1)|(b>>3).
__device__ __forceinline__ int kperm128(int i) {   // i = byte index
  int b = (i >> 3) & 15;
  int np = ((b & 7) << 1) | (b >> 3);
  return (i & ~127) | (np << 3) | (i & 7);
}

// ---------------- prep: adj -> adj8(fp8 x4096, 128B k-perm) + rowsum (blocks 0..4095)
// ----------------       x -> Xt8[s*32+f][j] fp8 (128B k-perm)
__global__ __launch_bounds__(256) void k_prep(const float* __restrict__ adj,
                                              unsigned char* __restrict__ adj8,
                                              float* __restrict__ rowsum,
                                              const float* __restrict__ x,
                                              unsigned char* __restrict__ Xt8) {
  __shared__ float xl[64][33];
  __shared__ float ps[4];
  int tid = threadIdx.x;
  if (blockIdx.x < 4096) {
    int row = blockIdx.x;
    const float4* src = (const float4*)(adj + (size_t)row * 4096);
    uchar4* dst8 = (uchar4*)(adj8 + (size_t)row * 4096);
    float sum = 0.f;
    #pragma unroll
    for (int q = 0; q < 4; ++q) {
      int idx = q * 256 + tid;              // uchar4 (4B) units
      float4 v = src[idx];
      uchar4 r8;
      r8.x = f2e4m3(v.x * 4096.f); r8.y = f2e4m3(v.y * 4096.f);
      r8.z = f2e4m3(v.z * 4096.f); r8.w = f2e4m3(v.w * 4096.f);
      int b = (idx >> 1) & 15;              // 8B block within 128B group
      int np = ((b & 7) << 1) | (b >> 3);
      int nidx = (idx & ~31) | (np << 1) | (idx & 1);
      dst8[nidx] = r8;
      sum += (v.x + v.y) + (v.z + v.w);
    }
    #pragma unroll
    for (int off = 1; off < 64; off <<= 1) sum += __shfl_xor(sum, off);
    if ((tid & 63) == 0) ps[tid >> 6] = sum;
    __syncthreads();
    if (tid == 0) rowsum[row] = (ps[0] + ps[1]) + (ps[2] + ps[3]);
    return;
  }
  int bs = blockIdx.x - 4096;
  int s = bs >> 6, jb = (bs & 63) << 6;
  const float4* xg = (const float4*)(x + ((size_t)s * NN + jb) * FF);
  #pragma unroll
  for (int ii = 0; ii < 2; ++ii) {
    int idx = tid + ii * 256;
    float4 v = xg[idx];
    int j = idx >> 3, f = (idx & 7) << 2;
    xl[j][f] = v.x; xl[j][f + 1] = v.y; xl[j][f + 2] = v.z; xl[j][f + 3] = v.w;
  }
  __syncthreads();
  int f = tid >> 3, jc = tid & 7;
  unsigned int lo = 0, hi = 0;
  #pragma unroll
  for (int jj = 0; jj < 4; ++jj) lo |= ((unsigned int)f2e4m3(xl[jc * 8 + jj][f])) << (jj * 8);
  #pragma unroll
  for (int jj = 0; jj < 4; ++jj) hi |= ((unsigned int)f2e4m3(xl[jc * 8 + 4 + jj][f])) << (jj * 8);
  uint2 ov; ov.x = lo; ov.y = hi;
  int np = (jc << 1) | ((jb >> 6) & 1);
  *(uint2*)(Xt8 + (size_t)(s * 32 + f) * 4096 + (jb & ~127) + np * 8) = ov;
}

// =====================================================================
// GEMM-AX fp8, BK=128 (round-17 proven, byte-identical)
// =====================================================================
#define SBAR()   asm volatile("s_barrier" ::: "memory")
#define VMC8()   asm volatile("s_waitcnt vmcnt(8)" ::: "memory")
#define VMC6()   asm volatile("s_waitcnt vmcnt(6)" ::: "memory")
#define VMC0()   asm volatile("s_waitcnt vmcnt(0)" ::: "memory")

__global__ __launch_bounds__(512, 2) void k_gemmAX(
    const unsigned char* __restrict__ A8,
    const unsigned char* __restrict__ B8,
    const float* __restrict__ rowsum,
    const float* __restrict__ W1f,
    const float* __restrict__ b1f,
    const float* __restrict__ W2f,
    const float* __restrict__ b2f,
    unsigned char* __restrict__ B2t8) {
  __shared__ __align__(16) char lds[147456];               // 3 x 48KB
  __shared__ __align__(16) unsigned short w1t[64 * 40];    // W1^T bf16, pad 40
  __shared__ float w2l[128];
  __shared__ float b1l[64];
  __shared__ float b2l[2];
  const int tid = threadIdx.x;
  const int wid = tid >> 6, l = tid & 63;
  const int wr2 = wid >> 2, wc2 = wid & 3;
  const int lc = l & 15, lq = l >> 4;

  {
    float4 v = ((const float4*)W1f)[tid];
    int f = tid >> 4, h = (tid & 15) * 4;
    w1t[(h + 0) * 40 + f] = f2bf(v.x);
    w1t[(h + 1) * 40 + f] = f2bf(v.y);
    w1t[(h + 2) * 40 + f] = f2bf(v.z);
    w1t[(h + 3) * 40 + f] = f2bf(v.w);
  }
  if (tid < 32) *(float4*)&w2l[tid * 4] = ((const float4*)W2f)[tid];
  if (tid < 16) *(float4*)&b1l[tid * 4] = ((const float4*)b1f)[tid];
  if (tid < 2) b2l[tid] = b2f[tid];
  __syncthreads();

  int bid = blockIdx.x;
  int swz = (bid & 7) * 32 + (bid >> 3);
  const int i0 = (swz >> 3) * 128;
  const int c0 = (swz & 7) * 256;

  const int aBase = (wr2 * 64 + lc) * 128;
  const int bBase = 16384 + (wc2 * 64 + lc) * 128;
  const int cLo = ((lq ^ (lc & 7)) << 4);
  const int cHi = (((4 + lq) ^ (lc & 7)) << 4);

  const int srow = wid * 8 + (l >> 3);
  const int scol = (((l & 7) ^ (srow & 7)) << 4);
  const char* gA = (const char*)A8 + (size_t)(i0 + srow) * 4096 + scol;
  const char* gB = (const char*)B8 + (size_t)(c0 + srow) * 4096 + scol;
  char* ldsW = (char*)lds + wid * 1024;
  const char* ldsR = (const char*)lds;

  f32x4 acc[4][4];
  #pragma unroll
  for (int m = 0; m < 4; ++m)
    #pragma unroll
    for (int n = 0; n < 4; ++n) acc[m][n] = {0.f, 0.f, 0.f, 0.f};

  longx2 afqL[4], bfqL[4], afqH[4], bfqH[4];

#define STAGE6(KT, BOFS) do {                                                        \
    __builtin_amdgcn_global_load_lds((const AS1 void*)(gA + (KT) * 128),             \
        (AS3 void*)(ldsW + (BOFS)), 16, 0, 0);                                       \
    __builtin_amdgcn_global_load_lds((const AS1 void*)(gA + 262144 + (KT) * 128),    \
        (AS3 void*)(ldsW + (BOFS) + 8192), 16, 0, 0);                                \
    __builtin_amdgcn_global_load_lds((const AS1 void*)(gB + (KT) * 128),             \
        (AS3 void*)(ldsW + (BOFS) + 16384), 16, 0, 0);                               \
    __builtin_amdgcn_global_load_lds((const AS1 void*)(gB + 262144 + (KT) * 128),    \
        (AS3 void*)(ldsW + (BOFS) + 24576), 16, 0, 0);                               \
    __builtin_amdgcn_global_load_lds((const AS1 void*)(gB + 524288 + (KT) * 128),    \
        (AS3 void*)(ldsW + (BOFS) + 32768), 16, 0, 0);                               \
    __builtin_amdgcn_global_load_lds((const AS1 void*)(gB + 786432 + (KT) * 128),    \
        (AS3 void*)(ldsW + (BOFS) + 40960), 16, 0, 0);                               \
  } while (0)

#define READ_ALL(BOFS) do {                                                          \
    _Pragma("unroll")                                                                \
    for (int _m = 0; _m < 4; ++_m) {                                                 \
      afqL[_m] = *(const longx2*)(ldsR + (BOFS) + aBase + _m * 2048 + cLo);          \
      afqH[_m] = *(const longx2*)(ldsR + (BOFS) + aBase + _m * 2048 + cHi);          \
    }                                                                                \
    _Pragma("unroll")                                                                \
    for (int _n = 0; _n < 4; ++_n) {                                                 \
      bfqL[_n] = *(const longx2*)(ldsR + (BOFS) + bBase + _n * 2048 + cLo);          \
      bfqH[_n] = *(const longx2*)(ldsR + (BOFS) + bBase + _n * 2048 + cHi);          \
    } } while (0)

#define MFMA_SET(AF, BF) do {                                                        \
    __builtin_amdgcn_s_setprio(1);                                                   \
    _Pragma("unroll")                                                                \
    for (int _kk = 0; _kk < 2; ++_kk)                                                \
      _Pragma("unroll")                                                              \
      for (int _m = 0; _m < 4; ++_m)                                                 \
        _Pragma("unroll")                                                            \
        for (int _n = 0; _n < 4; ++_n)                                               \
          acc[_m][_n] = __builtin_amdgcn_mfma_f32_16x16x32_fp8_fp8(                  \
              AF[_m][_kk], BF[_n][_kk], acc[_m][_n], 0, 0, 0);                       \
    __builtin_amdgcn_s_setprio(0);                                                   \
  } while (0)

  STAGE6(0, 0);
  STAGE6(1, 49152);
  VMC6();
  SBAR();

  int bR = 0, bS = 98304;
  for (int kt = 0; kt < 30; ++kt) {
    READ_ALL(bR);
    STAGE6(kt + 2, bS);
    MFMA_SET(afqL, bfqL);
    MFMA_SET(afqH, bfqH);
    VMC6();
    SBAR();
    bR = (bR == 98304) ? 0 : bR + 49152;
    bS = (bS == 98304) ? 0 : bS + 49152;
  }
  READ_ALL(bR); MFMA_SET(afqL, bfqL); MFMA_SET(afqH, bfqH);
  VMC0(); SBAR(); bR = (bR == 98304) ? 0 : bR + 49152;
  READ_ALL(bR); MFMA_SET(afqL, bfqL); MFMA_SET(afqH, bfqH);
  __syncthreads();

  unsigned short* C1L = (unsigned short*)lds;
  {
    const int rb = wr2 * 64 + lq * 4;
    const int cbL = wc2 * 64 + lc;
    #pragma unroll
    for (int m = 0; m < 4; ++m)
      #pragma unroll
      for (int r = 0; r < 4; ++r) {
        const int row = rb + m * 16 + r;
        #pragma unroll
        for (int n = 0; n < 4; ++n)
          C1L[row * 264 + cbL + n * 16] = f2bf(acc[m][n][r] * 0.000244140625f);
      }
  }
  __syncthreads();

  {
    const f32x4 zacc = {0.f, 0.f, 0.f, 0.f};
    bf16x8 bw[4];
    float b1v[4], w2a[4], w2b[4];
    #pragma unroll
    for (int n = 0; n < 4; ++n) {
      const int h = n * 16 + lc;
      bw[n] = *(const bf16x8*)((const char*)w1t + h * 80 + lq * 16);
      b1v[n] = b1l[h];
      w2a[n] = w2l[h * 2];
      w2b[n] = w2l[h * 2 + 1];
    }
    const int rbase = wid * 16 + lq * 4;
    const float4 rs4 = *(const float4*)&rowsum[i0 + rbase];
    const float bo0 = b2l[0], bo1 = b2l[1];
    #pragma unroll
    for (int s = 0; s < 8; ++s) {
      bf16x8 afe = *(const bf16x8*)((const char*)C1L +
                     (wid * 16 + lc) * 528 + s * 64 + lq * 16);
      float o0r[4] = {0.f, 0.f, 0.f, 0.f};
      float o1r[4] = {0.f, 0.f, 0.f, 0.f};
      #pragma unroll
      for (int n = 0; n < 4; ++n) {
        f32x4 hq = __builtin_amdgcn_mfma_f32_16x16x32_bf16(afe, bw[n], zacc, 0, 0, 0);
        #pragma unroll
        for (int r = 0; r < 4; ++r) {
          float hv = hq[r] + rs4[r] * b1v[n];
          hv = hv > 0.f ? hv : 0.f;
          o0r[r] += hv * w2a[n];
          o1r[r] += hv * w2b[n];
        }
      }
      #pragma unroll
      for (int off = 1; off < 16; off <<= 1)
        #pragma unroll
        for (int r = 0; r < 4; ++r) {
          o0r[r] += __shfl_xor(o0r[r], off);
          o1r[r] += __shfl_xor(o1r[r], off);
        }
      if (lc == 0) {
        const int sg = (c0 >> 5) + s;
        #pragma unroll
        for (int r = 0; r < 4; ++r) {
          const int ip = kperm128(i0 + rbase + r);
          B2t8[(size_t)(sg * 2 + 0) * 4096 + ip] = f2e4m3((o0r[r] + bo0) * 4096.f);
          B2t8[(size_t)(sg * 2 + 1) * 4096 + ip] = f2e4m3((o1r[r] + bo1) * 4096.f);
        }
      }
    }
  }
}

// =====================================================================
// GEMM2 fp8 split-K=4, K=1024/block (8 BK=128 tiles), gemmAX-proven
// rolled loop: 3x32KB buffers, dist-2, vmcnt(8).
// =====================================================================
__global__ __launch_bounds__(256) void k_gemm2f8(
    const unsigned char* __restrict__ A8,
    const unsigned char* __restrict__ B8,
    float* __restrict__ Gp) {
  __shared__ __align__(16) char lds[98304];   // 3 x 32KB
  const int tid = threadIdx.x;
  const int wid = tid >> 6, l = tid & 63;
  const int wr = wid >> 1, wc = wid & 1;
  const int lc = l & 15, lq = l >> 4;
  const int bi = blockIdx.x & 31, ks = blockIdx.x >> 5;   // ks in [0,4)
  const int i0 = bi * 128;
  const size_t kbase = (size_t)ks * 1024;

  const int aBase = (wr * 64 + lc) * 128;
  const int bBase = 16384 + (wc * 64 + lc) * 128;
  const int cLo = ((lq ^ (lc & 7)) << 4);
  const int cHi = (((4 + lq) ^ (lc & 7)) << 4);

  const int srow = wid * 8 + (l >> 3);
  const int scol = (((l & 7) ^ (srow & 7)) << 4);
  const char* gA = (const char*)A8 + (size_t)(i0 + srow) * 4096 + kbase + scol;
  const char* gB = (const char*)B8 + (size_t)srow * 4096 + kbase + scol;
  char* ldsW = (char*)lds + wid * 1024;
  const char* ldsR = (const char*)lds;

  f32x4 acc[4][4];
  #pragma unroll
  for (int m = 0; m < 4; ++m)
    #pragma unroll
    for (int n = 0; n < 4; ++n) acc[m][n] = {0.f, 0.f, 0.f, 0.f};

  longx2 afqL[4], bfqL[4], afqH[4], bfqH[4];

#define G2STAGE(KT, BOFS) do {                                                       \
    __builtin_amdgcn_global_load_lds((const AS1 void*)(gA + (KT) * 128),             \
        (AS3 void*)(ldsW + (BOFS)), 16, 0, 0);                                       \
    __builtin_amdgcn_global_load_lds((const AS1 void*)(gA + 131072 + (KT) * 128),    \
        (AS3 void*)(ldsW + (BOFS) + 4096), 16, 0, 0);                                \
    __builtin_amdgcn_global_load_lds((const AS1 void*)(gA + 262144 + (KT) * 128),    \
        (AS3 void*)(ldsW + (BOFS) + 8192), 16, 0, 0);                                \
    __builtin_amdgcn_global_load_lds((const AS1 void*)(gA + 393216 + (KT) * 128),    \
        (AS3 void*)(ldsW + (BOFS) + 12288), 16, 0, 0);                               \
    __builtin_amdgcn_global_load_lds((const AS1 void*)(gB + (KT) * 128),             \
        (AS3 void*)(ldsW + (BOFS) + 16384), 16, 0, 0);                               \
    __builtin_amdgcn_global_load_lds((const AS1 void*)(gB + 131072 + (KT) * 128),    \
        (AS3 void*)(ldsW + (BOFS) + 20480), 16, 0, 0);                               \
    __builtin_amdgcn_global_load_lds((const AS1 void*)(gB + 262144 + (KT) * 128),    \
        (AS3 void*)(ldsW + (BOFS) + 24576), 16, 0, 0);                               \
    __builtin_amdgcn_global_load_lds((const AS1 void*)(gB + 393216 + (KT) * 128),    \
        (AS3 void*)(ldsW + (BOFS) + 28672), 16, 0, 0);                               \
  } while (0)

#define G2READALL(BOFS) do {                                                         \
    _Pragma("unroll")                                                                \
    for (int _m = 0; _m < 4; ++_m) {                                                 \
      afqL[_m] = *(const longx2*)(ldsR + (BOFS) + aBase + _m * 2048 + cLo);          \
      afqH[_m] = *(const longx2*)(ldsR + (BOFS) + aBase + _m * 2048 + cHi);          \
    }                                                                                \
    _Pragma("unroll")                                                                \
    for (int _n = 0; _n < 4; ++_n) {                                                 \
      bfqL[_n] = *(const longx2*)(ldsR + (BOFS) + bBase + _n * 2048 + cLo);          \
      bfqH[_n] = *(const longx2*)(ldsR + (BOFS) + bBase + _n * 2048 + cHi);          \
    } } while (0)

#define G2MFMA(AF, BF) do {                                                          \
    __builtin_amdgcn_s_setprio(1);                                                   \
    _Pragma("unroll")                                                                \
    for (int _kk = 0; _kk < 2; ++_kk)                                                \
      _Pragma("unroll")                                                              \
      for (int _m = 0; _m < 4; ++_m)                                                 \
        _Pragma("unroll")                                                            \
        for (int _n = 0; _n < 4; ++_n)                                               \
          acc[_m][_n] = __builtin_amdgcn_mfma_f32_16x16x32_fp8_fp8(                  \
              AF[_m][_kk], BF[_n][_kk], acc[_m][_n], 0, 0, 0);                       \
    __builtin_amdgcn_s_setprio(0);                                                   \
  } while (0)

  G2STAGE(0, 0);
  G2STAGE(1, 32768);
  VMC8();
  SBAR();

  int bR = 0, bS = 65536;
  for (int kt = 0; kt < 6; ++kt) {
    G2READALL(bR);
    G2STAGE(kt + 2, bS);
    G2MFMA(afqL, bfqL);
    G2MFMA(afqH, bfqH);
    VMC8();
    SBAR();
    bR = (bR == 65536) ? 0 : bR + 32768;
    bS = (bS == 65536) ? 0 : bS + 32768;
  }
  G2READALL(bR); G2MFMA(afqL, bfqL); G2MFMA(afqH, bfqH);
  VMC0(); SBAR(); bR = (bR == 65536) ? 0 : bR + 32768;
  G2READALL(bR); G2MFMA(afqL, bfqL); G2MFMA(afqH, bfqH);

  float* outp = Gp + (size_t)ks * 524288;
  const int rbase = i0 + wr * 64 + lq * 4;
  const int cbase = wc * 64 + lc;
  #pragma unroll
  for (int m = 0; m < 4; ++m)
    #pragma unroll
    for (int n = 0; n < 4; ++n)
      #pragma unroll
      for (int r = 0; r < 4; ++r)
        outp[(size_t)(rbase + m * 16 + r) * 128 + cbase + n * 16] =
            acc[m][n][r] * 5.9604644775390625e-8f;   // 2^-24
}

// ---------------- reduce split-K(4) + log_softmax -> R[s][i*2+o] f32 ----------------
__global__ __launch_bounds__(256) void k_lsm(const float* __restrict__ Gp,
                                             float* __restrict__ Rm) {
  __shared__ float Gacc[32][130];
  int i0 = blockIdx.x * 32;
  int tid = threadIdx.x;
  float4 v[4];
  #pragma unroll
  for (int i = 0; i < 4; ++i) v[i] = {0.f, 0.f, 0.f, 0.f};
  for (int ks = 0; ks < 4; ++ks) {
    const float4* gp4 = ((const float4*)Gp) + (size_t)ks * 131072 + (size_t)i0 * 32;
    #pragma unroll
    for (int i = 0; i < 4; ++i) {
      float4 t = gp4[tid + i * 256];
      v[i].x += t.x; v[i].y += t.y; v[i].z += t.z; v[i].w += t.w;
    }
  }
  #pragma unroll
  for (int i = 0; i < 4; ++i) {
    int f4i = tid + i * 256, row = f4i >> 5, c = (f4i & 31) * 4;
    Gacc[row][c] = v[i].x; Gacc[row][c + 1] = v[i].y;
    Gacc[row][c + 2] = v[i].z; Gacc[row][c + 3] = v[i].w;
  }
  __syncthreads();
  #pragma unroll
  for (int j = 0; j < 8; ++j) {
    int p = j * 256 + tid;
    int ii = p & 31, s = p >> 5;
    float g0 = Gacc[ii][s * 2], g1 = Gacc[ii][s * 2 + 1];
    float m = fmaxf(g0, g1);
    float lse = m + logf(expf(g0 - m) + expf(g1 - m));
    float2 o_; o_.x = g0 - lse; o_.y = g1 - lse;
    *((float2*)(Rm + (size_t)s * 8192 + (size_t)(i0 + ii) * 2)) = o_;
  }
}

// ---------------- gi0 partial: part[ks][t][g] = R[t] . Wih0[g] over c-range ----------------
__global__ __launch_bounds__(256) void k_gi0(const float* __restrict__ Rm,
                                             const float* __restrict__ Wih0,
                                             float* __restrict__ part) {
  __shared__ float4 Wl[4 * 128];
  int gb = blockIdx.x % 48, ks = blockIdx.x / 48;
  int c0 = ks * 512;
  int tid = threadIdx.x;
  #pragma unroll
  for (int i = 0; i < 2; ++i) {
    int idx = tid + i * 256;
    int g = idx >> 7, c4 = idx & 127;
    Wl[g * 128 + c4] = ((const float4*)(Wih0 + (size_t)(gb * 4 + g) * 8192 + c0))[c4];
  }
  __syncthreads();
  int w = tid >> 6, lane = tid & 63;
  for (int pass = 0; pass < 16; ++pass) {
    int t = pass * 4 + w;
    float a0 = 0.f, a1 = 0.f, a2 = 0.f, a3 = 0.f;
    const float4* rg = (const float4*)(Rm + (size_t)t * 8192 + c0);
    #pragma unroll
    for (int i = 0; i < 2; ++i) {
      int c4 = i * 64 + lane;
      float4 r4 = rg[c4];
      float4 w0 = Wl[c4], w1 = Wl[128 + c4], w2 = Wl[256 + c4], w3 = Wl[384 + c4];
      a0 += r4.x * w0.x + r4.y * w0.y + r4.z * w0.z + r4.w * w0.w;
      a1 += r4.x * w1.x + r4.y * w1.y + r4.z * w1.z + r4.w * w1.w;
      a2 += r4.x * w2.x + r4.y * w2.y + r4.z * w2.z + r4.w * w2.w;
      a3 += r4.x * w3.x + r4.y * w3.y + r4.z * w3.z + r4.w * w3.w;
    }
    #pragma unroll
    for (int off = 1; off < 64; off <<= 1) {
      a0 += __shfl_xor(a0, off);
      a1 += __shfl_xor(a1, off);
      a2 += __shfl_xor(a2, off);
      a3 += __shfl_xor(a3, off);
    }
    if (lane == 0) {
      float4 o_; o_.x = a0; o_.y = a1; o_.z = a2; o_.w = a3;
      *((float4*)(part + ((size_t)ks * 64 + t) * 192 + gb * 4)) = o_;
    }
  }
}

__global__ __launch_bounds__(256) void k_gi0red(const float* __restrict__ part,
                                                const float* __restrict__ bih0,
                                                float* __restrict__ gi0) {
  int idx = blockIdx.x * 256 + threadIdx.x;
  if (idx < 12288) {
    float s_ = bih0[idx % 192];
    for (int ks = 0; ks < 16; ++ks) s_ += part[ks * 12288 + idx];
    gi0[idx] = s_;
  }
}

// =====================================================================
// MFMA GRU: 3 waves (one matvec each, 12 rowblocks/wave), 2 barriers/step
// (round-15 proven dataflow; wave partition halved for cheaper barriers).
// =====================================================================
__device__ __forceinline__ float fsigm(float x) {
  return __builtin_amdgcn_rcpf(1.f + __expf(-x));
}
__device__ __forceinline__ float ftanh(float x) {
  return 1.f - 2.f * __builtin_amdgcn_rcpf(1.f + __expf(2.f * x));
}

__global__ __launch_bounds__(192, 1) void k_gru(const float* __restrict__ gi0,
                                                const float* __restrict__ Whh0,
                                                const float* __restrict__ bhh0,
                                                const float* __restrict__ Wih1,
                                                const float* __restrict__ Whh1,
                                                const float* __restrict__ bih1,
                                                const float* __restrict__ bhh1,
                                                float* __restrict__ out) {
  __shared__ float gil[64][192];
  __shared__ float gout[576];
  __shared__ __align__(16) unsigned short hv[2][64];
  const int tid = threadIdx.x;
  const int w = tid >> 6, l = tid & 63;
  const int matw = w;                       // 0:Whh0@h0 1:Wih1@h0 2:Whh1@h1
  const float* Wm = (matw == 0) ? Whh0 : (matw == 1 ? Wih1 : Whh1);
  const int mi = (matw == 2) ? 1 : 0;
  const int lc = l & 15, lq = l >> 4;

  bf16x8 afr[12][2];
  #pragma unroll
  for (int rbi = 0; rbi < 12; ++rbi) {
    int g = rbi * 16 + lc;
    #pragma unroll
    for (int kh = 0; kh < 2; ++kh) {
      int k0 = kh * 32 + lq * 8;
      const float4* src = (const float4*)(Wm + (size_t)g * 64 + k0);
      float4 v0 = src[0], v1 = src[1];
      bf16x8 a;
      a[0] = (short)f2bf(v0.x); a[1] = (short)f2bf(v0.y);
      a[2] = (short)f2bf(v0.z); a[3] = (short)f2bf(v0.w);
      a[4] = (short)f2bf(v1.x); a[5] = (short)f2bf(v1.y);
      a[6] = (short)f2bf(v1.z); a[7] = (short)f2bf(v1.w);
      afr[rbi][kh] = a;
    }
  }
  {
    float4* gf = (float4*)&gil[0][0];
    const float4* gs = (const float4*)gi0;
    #pragma unroll
    for (int i = 0; i < 16; ++i) gf[i * 192 + tid] = gs[i * 192 + tid];
  }
  if (tid < 128) hv[tid >> 6][tid & 63] = 0;

  float hreg = 0.f;
  float bR = 0.f, bZ = 0.f, bNa = 0.f, bNb = 0.f;
  if (tid < 64) {
    bR = bhh0[tid]; bZ = bhh0[64 + tid]; bNa = bhh0[128 + tid];
  } else if (tid < 128) {
    int g = tid - 64;
    bR = bih1[g] + bhh1[g];
    bZ = bih1[64 + g] + bhh1[64 + g];
    bNa = bih1[128 + g];
    bNb = bhh1[128 + g];
  }
  asm volatile("s_waitcnt lgkmcnt(0)\n\ts_barrier" ::: "memory");

  const int gwb = matw * 192 + lq * 4;
  const f32x4 zacc = {0.f, 0.f, 0.f, 0.f};

  for (int i = 0; i <= 64; ++i) {
    bf16x8 b0 = *(const bf16x8*)&hv[mi][lq * 8];
    bf16x8 b1 = *(const bf16x8*)&hv[mi][32 + lq * 8];
    #pragma unroll
    for (int rbi = 0; rbi < 12; ++rbi) {
      f32x4 a_ = __builtin_amdgcn_mfma_f32_16x16x32_bf16(afr[rbi][0], b0, zacc, 0, 0, 0);
      a_ = __builtin_amdgcn_mfma_f32_16x16x32_bf16(afr[rbi][1], b1, a_, 0, 0, 0);
      if (lc == 0) *(f32x4*)&gout[gwb + rbi * 16] = a_;
    }
    asm volatile("s_waitcnt lgkmcnt(0)\n\ts_barrier" ::: "memory");
    if (tid < 64) {
      if (i < 64) {
        float r = fsigm(gil[i][tid] + gout[tid] + bR);
        float z = fsigm(gil[i][64 + tid] + gout[64 + tid] + bZ);
        float n = ftanh(gil[i][128 + tid] + r * (gout[128 + tid] + bNa));
        hreg = (1.f - z) * n + z * hreg;
        hv[0][tid] = f2bf(hreg);
      }
    } else if (tid < 128 && i > 0) {
      int g = tid - 64;
      float r = fsigm(gout[192 + g] + gout[384 + g] + bR);
      float z = fsigm(gout[256 + g] + gout[448 + g] + bZ);
      float n = ftanh((gout[320 + g] + bNa) + r * (gout[512 + g] + bNb));
      hreg = (1.f - z) * n + z * hreg;
      hv[1][g] = f2bf(hreg);
      out[(i - 1) * 64 + g] = hreg;
    }
    asm volatile("s_waitcnt lgkmcnt(0)\n\ts_barrier" ::: "memory");
  }
  if (tid < 64) out[4096 + tid] = hreg;
  else if (tid < 128) out[4096 + 64 + (tid - 64)] = hreg;
}

extern "C" void kernel_launch(void* const* d_in, const int* in_sizes, int n_in,
                              void* d_out, int out_size, void* d_ws, size_t ws_size,
                              hipStream_t stream) {
  const float* x    = (const float*)d_in[0];
  const float* adj  = (const float*)d_in[1];
  const float* W1   = (const float*)d_in[2];
  const float* b1   = (const float*)d_in[3];
  const float* W2   = (const float*)d_in[4];
  const float* b2   = (const float*)d_in[5];
  const float* Wih0 = (const float*)d_in[6];
  const float* Whh0 = (const float*)d_in[7];
  const float* bih0 = (const float*)d_in[8];
  const float* bhh0 = (const float*)d_in[9];
  const float* Wih1 = (const float*)d_in[10];
  const float* Whh1 = (const float*)d_in[11];
  const float* bih1 = (const float*)d_in[12];
  const float* bhh1 = (const float*)d_in[13];
  float* out = (float*)d_out;

  char* ws = (char*)d_ws;
  unsigned char* adj8  = (unsigned char*)ws;                       // 16.78MB
  unsigned char* Xt8   = (unsigned char*)(ws + 16777216);          // 8.39MB
  float* rowsum        = (float*)(ws + 25165824);                  // 16KB
  float* Gp            = (float*)(ws + 25182208);                  // 8.39MB (4 slices)
  float* Rm            = (float*)(ws + 41959424);                  // 2MB
  float* part          = (float*)(ws + 44056576);                  // 768KB
  float* gi0           = (float*)(ws + 44843008);                  // 48KB
  unsigned char* B2t8  = (unsigned char*)(ws + 44892160);          // 512KB

  k_prep<<<8192, 256, 0, stream>>>(adj, adj8, rowsum, x, Xt8);
  k_gemmAX<<<256, 512, 0, stream>>>(adj8, Xt8, rowsum, W1, b1, W2, b2, B2t8);
  k_gemm2f8<<<128, 256, 0, stream>>>(adj8, B2t8, Gp);
  k_lsm<<<128, 256, 0, stream>>>(Gp, Rm);
  k_gi0<<<768, 256, 0, stream>>>(Rm, Wih0, part);
  k_gi0red<<<48, 256, 0, stream>>>(part, bih0, gi0);
  k_gru<<<1, 192, 0, stream>>>(gi0, Whh0, bhh0, Wih1, Whh1, bih1, bhh1, out);
}

// Round 19
// 148.328 us; speedup vs baseline: 1.0710x; 1.0710x over previous
//
#include <hip/hip_runtime.h>
#include <stdint.h>

#define SS 64
#define NN 4096
#define FF 32
#define HH 64
#define OO 2
#define G3 192

typedef float f32x4 __attribute__((ext_vector_type(4)));
typedef short bf16x8 __attribute__((ext_vector_type(8)));
typedef unsigned short u16x8 __attribute__((ext_vector_type(8)));
typedef long longx2 __attribute__((ext_vector_type(2)));

#define AS1 __attribute__((address_space(1)))
#define AS3 __attribute__((address_space(3)))

__device__ __forceinline__ unsigned short f2bf(float f) {
  union { float f; uint32_t u; } v; v.f = f;
  uint32_t u = v.u;
  uint32_t r = (u + 0x7FFFu + ((u >> 16) & 1u)) >> 16;
  return (unsigned short)r;
}
__device__ __forceinline__ float bf2f(unsigned short s) {
  union { uint32_t u; float f; } v; v.u = ((uint32_t)s) << 16;
  return v.f;
}
// f32 -> OCP e4m3fn, RNE
__device__ __forceinline__ unsigned char f2e4m3(float x) {
  float a = fabsf(x);
  unsigned s = (x < 0.f) ? 0x80u : 0u;
  if (a >= 448.f) return (unsigned char)(s | 0x7E);
  if (a < 0.015625f) {
    int q = (int)rintf(a * 512.f);
    return (unsigned char)(s | (unsigned)q);
  }
  union { float f; uint32_t u; } v; v.f = a;
  uint32_t b = v.u + 0x7FFFFu + ((v.u >> 20) & 1u);
  int e = (int)(b >> 23) - 127;
  if (e > 8) return (unsigned char)(s | 0x7E);
  return (unsigned char)(s | (unsigned)(((e + 7) << 3) | ((b >> 20) & 7u)));
}
// k-permutation within a 128B group: 8B block b (0..15) -> ((b&7)<<1)|(b>>3).
__device__ __forceinline__ int kperm128(int i) {   // i = byte index
  int b = (i >> 3) & 15;
  int np = ((b & 7) << 1) | (b >> 3);
  return (i & ~127) | (np << 3) | (i & 7);
}

// ---------------- prep: adj -> adj8(fp8 x4096, 128B k-perm) + rowsum (blocks 0..4095)
// ----------------       x -> Xt8[s*32+f][j] fp8 (128B k-perm)
__global__ __launch_bounds__(256) void k_prep(const float* __restrict__ adj,
                                              unsigned char* __restrict__ adj8,
                                              float* __restrict__ rowsum,
                                              const float* __restrict__ x,
                                              unsigned char* __restrict__ Xt8) {
  __shared__ float xl[64][33];
  __shared__ float ps[4];
  int tid = threadIdx.x;
  if (blockIdx.x < 4096) {
    int row = blockIdx.x;
    const float4* src = (const float4*)(adj + (size_t)row * 4096);
    uchar4* dst8 = (uchar4*)(adj8 + (size_t)row * 4096);
    float sum = 0.f;
    #pragma unroll
    for (int q = 0; q < 4; ++q) {
      int idx = q * 256 + tid;              // uchar4 (4B) units
      float4 v = src[idx];
      uchar4 r8;
      r8.x = f2e4m3(v.x * 4096.f); r8.y = f2e4m3(v.y * 4096.f);
      r8.z = f2e4m3(v.z * 4096.f); r8.w = f2e4m3(v.w * 4096.f);
      int b = (idx >> 1) & 15;              // 8B block within 128B group
      int np = ((b & 7) << 1) | (b >> 3);
      int nidx = (idx & ~31) | (np << 1) | (idx & 1);
      dst8[nidx] = r8;
      sum += (v.x + v.y) + (v.z + v.w);
    }
    #pragma unroll
    for (int off = 1; off < 64; off <<= 1) sum += __shfl_xor(sum, off);
    if ((tid & 63) == 0) ps[tid >> 6] = sum;
    __syncthreads();
    if (tid == 0) rowsum[row] = (ps[0] + ps[1]) + (ps[2] + ps[3]);
    return;
  }
  int bs = blockIdx.x - 4096;
  int s = bs >> 6, jb = (bs & 63) << 6;
  const float4* xg = (const float4*)(x + ((size_t)s * NN + jb) * FF);
  #pragma unroll
  for (int ii = 0; ii < 2; ++ii) {
    int idx = tid + ii * 256;
    float4 v = xg[idx];
    int j = idx >> 3, f = (idx & 7) << 2;
    xl[j][f] = v.x; xl[j][f + 1] = v.y; xl[j][f + 2] = v.z; xl[j][f + 3] = v.w;
  }
  __syncthreads();
  int f = tid >> 3, jc = tid & 7;
  unsigned int lo = 0, hi = 0;
  #pragma unroll
  for (int jj = 0; jj < 4; ++jj) lo |= ((unsigned int)f2e4m3(xl[jc * 8 + jj][f])) << (jj * 8);
  #pragma unroll
  for (int jj = 0; jj < 4; ++jj) hi |= ((unsigned int)f2e4m3(xl[jc * 8 + 4 + jj][f])) << (jj * 8);
  uint2 ov; ov.x = lo; ov.y = hi;
  int np = (jc << 1) | ((jb >> 6) & 1);
  *(uint2*)(Xt8 + (size_t)(s * 32 + f) * 4096 + (jb & ~127) + np * 8) = ov;
}

// =====================================================================
// GEMM-AX fp8, BK=128 (round-17 proven, byte-identical)
// =====================================================================
#define SBAR()   asm volatile("s_barrier" ::: "memory")
#define VMC8()   asm volatile("s_waitcnt vmcnt(8)" ::: "memory")
#define VMC6()   asm volatile("s_waitcnt vmcnt(6)" ::: "memory")
#define VMC0()   asm volatile("s_waitcnt vmcnt(0)" ::: "memory")

__global__ __launch_bounds__(512, 2) void k_gemmAX(
    const unsigned char* __restrict__ A8,
    const unsigned char* __restrict__ B8,
    const float* __restrict__ rowsum,
    const float* __restrict__ W1f,
    const float* __restrict__ b1f,
    const float* __restrict__ W2f,
    const float* __restrict__ b2f,
    unsigned char* __restrict__ B2t8) {
  __shared__ __align__(16) char lds[147456];               // 3 x 48KB
  __shared__ __align__(16) unsigned short w1t[64 * 40];    // W1^T bf16, pad 40
  __shared__ float w2l[128];
  __shared__ float b1l[64];
  __shared__ float b2l[2];
  const int tid = threadIdx.x;
  const int wid = tid >> 6, l = tid & 63;
  const int wr2 = wid >> 2, wc2 = wid & 3;
  const int lc = l & 15, lq = l >> 4;

  {
    float4 v = ((const float4*)W1f)[tid];
    int f = tid >> 4, h = (tid & 15) * 4;
    w1t[(h + 0) * 40 + f] = f2bf(v.x);
    w1t[(h + 1) * 40 + f] = f2bf(v.y);
    w1t[(h + 2) * 40 + f] = f2bf(v.z);
    w1t[(h + 3) * 40 + f] = f2bf(v.w);
  }
  if (tid < 32) *(float4*)&w2l[tid * 4] = ((const float4*)W2f)[tid];
  if (tid < 16) *(float4*)&b1l[tid * 4] = ((const float4*)b1f)[tid];
  if (tid < 2) b2l[tid] = b2f[tid];
  __syncthreads();

  int bid = blockIdx.x;
  int swz = (bid & 7) * 32 + (bid >> 3);
  const int i0 = (swz >> 3) * 128;
  const int c0 = (swz & 7) * 256;

  const int aBase = (wr2 * 64 + lc) * 128;
  const int bBase = 16384 + (wc2 * 64 + lc) * 128;
  const int cLo = ((lq ^ (lc & 7)) << 4);
  const int cHi = (((4 + lq) ^ (lc & 7)) << 4);

  const int srow = wid * 8 + (l >> 3);
  const int scol = (((l & 7) ^ (srow & 7)) << 4);
  const char* gA = (const char*)A8 + (size_t)(i0 + srow) * 4096 + scol;
  const char* gB = (const char*)B8 + (size_t)(c0 + srow) * 4096 + scol;
  char* ldsW = (char*)lds + wid * 1024;
  const char* ldsR = (const char*)lds;

  f32x4 acc[4][4];
  #pragma unroll
  for (int m = 0; m < 4; ++m)
    #pragma unroll
    for (int n = 0; n < 4; ++n) acc[m][n] = {0.f, 0.f, 0.f, 0.f};

  longx2 afqL[4], bfqL[4], afqH[4], bfqH[4];

#define STAGE6(KT, BOFS) do {                                                        \
    __builtin_amdgcn_global_load_lds((const AS1 void*)(gA + (KT) * 128),             \
        (AS3 void*)(ldsW + (BOFS)), 16, 0, 0);                                       \
    __builtin_amdgcn_global_load_lds((const AS1 void*)(gA + 262144 + (KT) * 128),    \
        (AS3 void*)(ldsW + (BOFS) + 8192), 16, 0, 0);                                \
    __builtin_amdgcn_global_load_lds((const AS1 void*)(gB + (KT) * 128),             \
        (AS3 void*)(ldsW + (BOFS) + 16384), 16, 0, 0);                               \
    __builtin_amdgcn_global_load_lds((const AS1 void*)(gB + 262144 + (KT) * 128),    \
        (AS3 void*)(ldsW + (BOFS) + 24576), 16, 0, 0);                               \
    __builtin_amdgcn_global_load_lds((const AS1 void*)(gB + 524288 + (KT) * 128),    \
        (AS3 void*)(ldsW + (BOFS) + 32768), 16, 0, 0);                               \
    __builtin_amdgcn_global_load_lds((const AS1 void*)(gB + 786432 + (KT) * 128),    \
        (AS3 void*)(ldsW + (BOFS) + 40960), 16, 0, 0);                               \
  } while (0)

#define READ_ALL(BOFS) do {                                                          \
    _Pragma("unroll")                                                                \
    for (int _m = 0; _m < 4; ++_m) {                                                 \
      afqL[_m] = *(const longx2*)(ldsR + (BOFS) + aBase + _m * 2048 + cLo);          \
      afqH[_m] = *(const longx2*)(ldsR + (BOFS) + aBase + _m * 2048 + cHi);          \
    }                                                                                \
    _Pragma("unroll")                                                                \
    for (int _n = 0; _n < 4; ++_n) {                                                 \
      bfqL[_n] = *(const longx2*)(ldsR + (BOFS) + bBase + _n * 2048 + cLo);          \
      bfqH[_n] = *(const longx2*)(ldsR + (BOFS) + bBase + _n * 2048 + cHi);          \
    } } while (0)

#define MFMA_SET(AF, BF) do {                                                        \
    __builtin_amdgcn_s_setprio(1);                                                   \
    _Pragma("unroll")                                                                \
    for (int _kk = 0; _kk < 2; ++_kk)                                                \
      _Pragma("unroll")                                                              \
      for (int _m = 0; _m < 4; ++_m)                                                 \
        _Pragma("unroll")                                                            \
        for (int _n = 0; _n < 4; ++_n)                                               \
          acc[_m][_n] = __builtin_amdgcn_mfma_f32_16x16x32_fp8_fp8(                  \
              AF[_m][_kk], BF[_n][_kk], acc[_m][_n], 0, 0, 0);                       \
    __builtin_amdgcn_s_setprio(0);                                                   \
  } while (0)

  STAGE6(0, 0);
  STAGE6(1, 49152);
  VMC6();
  SBAR();

  int bR = 0, bS = 98304;
  for (int kt = 0; kt < 30; ++kt) {
    READ_ALL(bR);
    STAGE6(kt + 2, bS);
    MFMA_SET(afqL, bfqL);
    MFMA_SET(afqH, bfqH);
    VMC6();
    SBAR();
    bR = (bR == 98304) ? 0 : bR + 49152;
    bS = (bS == 98304) ? 0 : bS + 49152;
  }
  READ_ALL(bR); MFMA_SET(afqL, bfqL); MFMA_SET(afqH, bfqH);
  VMC0(); SBAR(); bR = (bR == 98304) ? 0 : bR + 49152;
  READ_ALL(bR); MFMA_SET(afqL, bfqL); MFMA_SET(afqH, bfqH);
  __syncthreads();

  unsigned short* C1L = (unsigned short*)lds;
  {
    const int rb = wr2 * 64 + lq * 4;
    const int cbL = wc2 * 64 + lc;
    #pragma unroll
    for (int m = 0; m < 4; ++m)
      #pragma unroll
      for (int r = 0; r < 4; ++r) {
        const int row = rb + m * 16 + r;
        #pragma unroll
        for (int n = 0; n < 4; ++n)
          C1L[row * 264 + cbL + n * 16] = f2bf(acc[m][n][r] * 0.000244140625f);
      }
  }
  __syncthreads();

  {
    const f32x4 zacc = {0.f, 0.f, 0.f, 0.f};
    bf16x8 bw[4];
    float b1v[4], w2a[4], w2b[4];
    #pragma unroll
    for (int n = 0; n < 4; ++n) {
      const int h = n * 16 + lc;
      bw[n] = *(const bf16x8*)((const char*)w1t + h * 80 + lq * 16);
      b1v[n] = b1l[h];
      w2a[n] = w2l[h * 2];
      w2b[n] = w2l[h * 2 + 1];
    }
    const int rbase = wid * 16 + lq * 4;
    const float4 rs4 = *(const float4*)&rowsum[i0 + rbase];
    const float bo0 = b2l[0], bo1 = b2l[1];
    #pragma unroll
    for (int s = 0; s < 8; ++s) {
      bf16x8 afe = *(const bf16x8*)((const char*)C1L +
                     (wid * 16 + lc) * 528 + s * 64 + lq * 16);
      float o0r[4] = {0.f, 0.f, 0.f, 0.f};
      float o1r[4] = {0.f, 0.f, 0.f, 0.f};
      #pragma unroll
      for (int n = 0; n < 4; ++n) {
        f32x4 hq = __builtin_amdgcn_mfma_f32_16x16x32_bf16(afe, bw[n], zacc, 0, 0, 0);
        #pragma unroll
        for (int r = 0; r < 4; ++r) {
          float hv = hq[r] + rs4[r] * b1v[n];
          hv = hv > 0.f ? hv : 0.f;
          o0r[r] += hv * w2a[n];
          o1r[r] += hv * w2b[n];
        }
      }
      #pragma unroll
      for (int off = 1; off < 16; off <<= 1)
        #pragma unroll
        for (int r = 0; r < 4; ++r) {
          o0r[r] += __shfl_xor(o0r[r], off);
          o1r[r] += __shfl_xor(o1r[r], off);
        }
      if (lc == 0) {
        const int sg = (c0 >> 5) + s;
        #pragma unroll
        for (int r = 0; r < 4; ++r) {
          const int ip = kperm128(i0 + rbase + r);
          B2t8[(size_t)(sg * 2 + 0) * 4096 + ip] = f2e4m3((o0r[r] + bo0) * 4096.f);
          B2t8[(size_t)(sg * 2 + 1) * 4096 + ip] = f2e4m3((o1r[r] + bo1) * 4096.f);
        }
      }
    }
  }
}

// =====================================================================
// GEMM2 fp8 split-K=8, BK=128 (round-15/17 proven, byte-identical)
// =====================================================================
__global__ __launch_bounds__(256) void k_gemm2f8(
    const unsigned char* __restrict__ A8,
    const unsigned char* __restrict__ B8,
    float* __restrict__ Gp) {
  __shared__ __align__(16) char lds[98304];   // 3 x 32KB
  const int tid = threadIdx.x;
  const int wid = tid >> 6, l = tid & 63;
  const int wr = wid >> 1, wc = wid & 1;
  const int lc = l & 15, lq = l >> 4;
  const int bi = blockIdx.x & 31, ks = blockIdx.x >> 5;
  const int i0 = bi * 128;
  const size_t kbase = (size_t)ks * 512;

  const int aBase = (wr * 64 + lc) * 128;
  const int bBase = 16384 + (wc * 64 + lc) * 128;
  const int cLo = ((lq ^ (lc & 7)) << 4);
  const int cHi = (((4 + lq) ^ (lc & 7)) << 4);

  const int srow = wid * 8 + (l >> 3);
  const int scol = (((l & 7) ^ (srow & 7)) << 4);
  const char* gA = (const char*)A8 + (size_t)(i0 + srow) * 4096 + kbase + scol;
  const char* gB = (const char*)B8 + (size_t)srow * 4096 + kbase + scol;
  char* ldsW = (char*)lds + wid * 1024;
  const char* ldsR = (const char*)lds;

  f32x4 acc[4][4];
  #pragma unroll
  for (int m = 0; m < 4; ++m)
    #pragma unroll
    for (int n = 0; n < 4; ++n) acc[m][n] = {0.f, 0.f, 0.f, 0.f};

  longx2 afqL[4], bfqL[4], afqH[4], bfqH[4];

#define G2STAGE(KT, BOFS) do {                                                       \
    __builtin_amdgcn_global_load_lds((const AS1 void*)(gA + (KT) * 128),             \
        (AS3 void*)(ldsW + (BOFS)), 16, 0, 0);                                       \
    __builtin_amdgcn_global_load_lds((const AS1 void*)(gA + 131072 + (KT) * 128),    \
        (AS3 void*)(ldsW + (BOFS) + 4096), 16, 0, 0);                                \
    __builtin_amdgcn_global_load_lds((const AS1 void*)(gA + 262144 + (KT) * 128),    \
        (AS3 void*)(ldsW + (BOFS) + 8192), 16, 0, 0);                                \
    __builtin_amdgcn_global_load_lds((const AS1 void*)(gA + 393216 + (KT) * 128),    \
        (AS3 void*)(ldsW + (BOFS) + 12288), 16, 0, 0);                               \
    __builtin_amdgcn_global_load_lds((const AS1 void*)(gB + (KT) * 128),             \
        (AS3 void*)(ldsW + (BOFS) + 16384), 16, 0, 0);                               \
    __builtin_amdgcn_global_load_lds((const AS1 void*)(gB + 131072 + (KT) * 128),    \
        (AS3 void*)(ldsW + (BOFS) + 20480), 16, 0, 0);                               \
    __builtin_amdgcn_global_load_lds((const AS1 void*)(gB + 262144 + (KT) * 128),    \
        (AS3 void*)(ldsW + (BOFS) + 24576), 16, 0, 0);                               \
    __builtin_amdgcn_global_load_lds((const AS1 void*)(gB + 393216 + (KT) * 128),    \
        (AS3 void*)(ldsW + (BOFS) + 28672), 16, 0, 0);                               \
  } while (0)

#define G2READALL(BOFS) do {                                                         \
    _Pragma("unroll")                                                                \
    for (int _m = 0; _m < 4; ++_m) {                                                 \
      afqL[_m] = *(const longx2*)(ldsR + (BOFS) + aBase + _m * 2048 + cLo);          \
      afqH[_m] = *(const longx2*)(ldsR + (BOFS) + aBase + _m * 2048 + cHi);          \
    }                                                                                \
    _Pragma("unroll")                                                                \
    for (int _n = 0; _n < 4; ++_n) {                                                 \
      bfqL[_n] = *(const longx2*)(ldsR + (BOFS) + bBase + _n * 2048 + cLo);          \
      bfqH[_n] = *(const longx2*)(ldsR + (BOFS) + bBase + _n * 2048 + cHi);          \
    } } while (0)

#define G2MFMA(AF, BF) do {                                                          \
    __builtin_amdgcn_s_setprio(1);                                                   \
    _Pragma("unroll")                                                                \
    for (int _kk = 0; _kk < 2; ++_kk)                                                \
      _Pragma("unroll")                                                              \
      for (int _m = 0; _m < 4; ++_m)                                                 \
        _Pragma("unroll")                                                            \
        for (int _n = 0; _n < 4; ++_n)                                               \
          acc[_m][_n] = __builtin_amdgcn_mfma_f32_16x16x32_fp8_fp8(                  \
              AF[_m][_kk], BF[_n][_kk], acc[_m][_n], 0, 0, 0);                       \
    __builtin_amdgcn_s_setprio(0);                                                   \
  } while (0)

  G2STAGE(0, 0);
  G2STAGE(1, 32768);
  VMC8();
  SBAR();

  G2READALL(0); G2STAGE(2, 65536); G2MFMA(afqL, bfqL); G2MFMA(afqH, bfqH);
  VMC8(); SBAR();
  G2READALL(32768); G2STAGE(3, 0); G2MFMA(afqL, bfqL); G2MFMA(afqH, bfqH);
  VMC8(); SBAR();
  G2READALL(65536); G2MFMA(afqL, bfqL); G2MFMA(afqH, bfqH);
  VMC0(); SBAR();
  G2READALL(0); G2MFMA(afqL, bfqL); G2MFMA(afqH, bfqH);

  float* outp = Gp + (size_t)ks * 524288;
  const int rbase = i0 + wr * 64 + lq * 4;
  const int cbase = wc * 64 + lc;
  #pragma unroll
  for (int m = 0; m < 4; ++m)
    #pragma unroll
    for (int n = 0; n < 4; ++n)
      #pragma unroll
      for (int r = 0; r < 4; ++r)
        outp[(size_t)(rbase + m * 16 + r) * 128 + cbase + n * 16] =
            acc[m][n][r] * 5.9604644775390625e-8f;   // 2^-24
}

// ---------------- reduce split-K(8) + log_softmax -> R[s][i*2+o] f32 ----------------
__global__ __launch_bounds__(256) void k_lsm(const float* __restrict__ Gp,
                                             float* __restrict__ Rm) {
  __shared__ float Gacc[32][130];
  int i0 = blockIdx.x * 32;
  int tid = threadIdx.x;
  float4 v[4];
  #pragma unroll
  for (int i = 0; i < 4; ++i) v[i] = {0.f, 0.f, 0.f, 0.f};
  for (int ks = 0; ks < 8; ++ks) {
    const float4* gp4 = ((const float4*)Gp) + (size_t)ks * 131072 + (size_t)i0 * 32;
    #pragma unroll
    for (int i = 0; i < 4; ++i) {
      float4 t = gp4[tid + i * 256];
      v[i].x += t.x; v[i].y += t.y; v[i].z += t.z; v[i].w += t.w;
    }
  }
  #pragma unroll
  for (int i = 0; i < 4; ++i) {
    int f4i = tid + i * 256, row = f4i >> 5, c = (f4i & 31) * 4;
    Gacc[row][c] = v[i].x; Gacc[row][c + 1] = v[i].y;
    Gacc[row][c + 2] = v[i].z; Gacc[row][c + 3] = v[i].w;
  }
  __syncthreads();
  #pragma unroll
  for (int j = 0; j < 8; ++j) {
    int p = j * 256 + tid;
    int ii = p & 31, s = p >> 5;
    float g0 = Gacc[ii][s * 2], g1 = Gacc[ii][s * 2 + 1];
    float m = fmaxf(g0, g1);
    float lse = m + logf(expf(g0 - m) + expf(g1 - m));
    float2 o_; o_.x = g0 - lse; o_.y = g1 - lse;
    *((float2*)(Rm + (size_t)s * 8192 + (size_t)(i0 + ii) * 2)) = o_;
  }
}

// ---------------- gi0 partial: part[ks][t][g] = R[t] . Wih0[g] over c-range ----------------
__global__ __launch_bounds__(256) void k_gi0(const float* __restrict__ Rm,
                                             const float* __restrict__ Wih0,
                                             float* __restrict__ part) {
  __shared__ float4 Wl[4 * 128];
  int gb = blockIdx.x % 48, ks = blockIdx.x / 48;
  int c0 = ks * 512;
  int tid = threadIdx.x;
  #pragma unroll
  for (int i = 0; i < 2; ++i) {
    int idx = tid + i * 256;
    int g = idx >> 7, c4 = idx & 127;
    Wl[g * 128 + c4] = ((const float4*)(Wih0 + (size_t)(gb * 4 + g) * 8192 + c0))[c4];
  }
  __syncthreads();
  int w = tid >> 6, lane = tid & 63;
  for (int pass = 0; pass < 16; ++pass) {
    int t = pass * 4 + w;
    float a0 = 0.f, a1 = 0.f, a2 = 0.f, a3 = 0.f;
    const float4* rg = (const float4*)(Rm + (size_t)t * 8192 + c0);
    #pragma unroll
    for (int i = 0; i < 2; ++i) {
      int c4 = i * 64 + lane;
      float4 r4 = rg[c4];
      float4 w0 = Wl[c4], w1 = Wl[128 + c4], w2 = Wl[256 + c4], w3 = Wl[384 + c4];
      a0 += r4.x * w0.x + r4.y * w0.y + r4.z * w0.z + r4.w * w0.w;
      a1 += r4.x * w1.x + r4.y * w1.y + r4.z * w1.z + r4.w * w1.w;
      a2 += r4.x * w2.x + r4.y * w2.y + r4.z * w2.z + r4.w * w2.w;
      a3 += r4.x * w3.x + r4.y * w3.y + r4.z * w3.z + r4.w * w3.w;
    }
    #pragma unroll
    for (int off = 1; off < 64; off <<= 1) {
      a0 += __shfl_xor(a0, off);
      a1 += __shfl_xor(a1, off);
      a2 += __shfl_xor(a2, off);
      a3 += __shfl_xor(a3, off);
    }
    if (lane == 0) {
      float4 o_; o_.x = a0; o_.y = a1; o_.z = a2; o_.w = a3;
      *((float4*)(part + ((size_t)ks * 64 + t) * 192 + gb * 4)) = o_;
    }
  }
}

__global__ __launch_bounds__(256) void k_gi0red(const float* __restrict__ part,
                                                const float* __restrict__ bih0,
                                                float* __restrict__ gi0) {
  int idx = blockIdx.x * 256 + threadIdx.x;
  if (idx < 12288) {
    float s_ = bih0[idx % 192];
    for (int ks = 0; ks < 16; ++ks) s_ += part[ks * 12288 + idx];
    gi0[idx] = s_;
  }
}

// =====================================================================
// MFMA GRU (round-15 proven: 6 waves, 2 barriers/step, shared hv)
// =====================================================================
__device__ __forceinline__ float fsigm(float x) {
  return __builtin_amdgcn_rcpf(1.f + __expf(-x));
}
__device__ __forceinline__ float ftanh(float x) {
  return 1.f - 2.f * __builtin_amdgcn_rcpf(1.f + __expf(2.f * x));
}

__global__ __launch_bounds__(384) void k_gru(const float* __restrict__ gi0,
                                             const float* __restrict__ Whh0,
                                             const float* __restrict__ bhh0,
                                             const float* __restrict__ Wih1,
                                             const float* __restrict__ Whh1,
                                             const float* __restrict__ bih1,
                                             const float* __restrict__ bhh1,
                                             float* __restrict__ out) {
  __shared__ float gil[64][192];
  __shared__ float gout[576];
  __shared__ __align__(16) unsigned short hv[2][64];
  const int tid = threadIdx.x;
  const int w = tid >> 6, l = tid & 63;
  const int matw = w >> 1, half = w & 1;
  const float* Wm = (matw == 0) ? Whh0 : (matw == 1 ? Wih1 : Whh1);
  const int mi = (matw == 2) ? 1 : 0;

  bf16x8 afr[6][2];
  #pragma unroll
  for (int rbi = 0; rbi < 6; ++rbi) {
    int g = (half * 6 + rbi) * 16 + (l & 15);
    #pragma unroll
    for (int kh = 0; kh < 2; ++kh) {
      int k0 = kh * 32 + (l >> 4) * 8;
      const float4* src = (const float4*)(Wm + (size_t)g * 64 + k0);
      float4 v0 = src[0], v1 = src[1];
      bf16x8 a;
      a[0] = (short)f2bf(v0.x); a[1] = (short)f2bf(v0.y);
      a[2] = (short)f2bf(v0.z); a[3] = (short)f2bf(v0.w);
      a[4] = (short)f2bf(v1.x); a[5] = (short)f2bf(v1.y);
      a[6] = (short)f2bf(v1.z); a[7] = (short)f2bf(v1.w);
      afr[rbi][kh] = a;
    }
  }
  {
    float4* gf = (float4*)&gil[0][0];
    const float4* gs = (const float4*)gi0;
    #pragma unroll
    for (int i = 0; i < 8; ++i) gf[i * 384 + tid] = gs[i * 384 + tid];
  }
  if (tid < 128) hv[tid >> 6][tid & 63] = 0;

  float hreg = 0.f;
  float bR = 0.f, bZ = 0.f, bNa = 0.f, bNb = 0.f;
  if (tid < 64) {
    bR = bhh0[tid]; bZ = bhh0[64 + tid]; bNa = bhh0[128 + tid];
  } else if (tid < 128) {
    int g = tid - 64;
    bR = bih1[g] + bhh1[g];
    bZ = bih1[64 + g] + bhh1[64 + g];
    bNa = bih1[128 + g];
    bNb = bhh1[128 + g];
  }
  asm volatile("s_waitcnt lgkmcnt(0)\n\ts_barrier" ::: "memory");

  const int gwb = matw * 192 + half * 96 + (l >> 4) * 4;
  const f32x4 zacc = {0.f, 0.f, 0.f, 0.f};

  for (int i = 0; i <= 64; ++i) {
    bf16x8 b0 = *(const bf16x8*)&hv[mi][(l >> 4) * 8];
    bf16x8 b1 = *(const bf16x8*)&hv[mi][32 + (l >> 4) * 8];
    #pragma unroll
    for (int rbi = 0; rbi < 6; ++rbi) {
      f32x4 a_ = __builtin_amdgcn_mfma_f32_16x16x32_bf16(afr[rbi][0], b0, zacc, 0, 0, 0);
      a_ = __builtin_amdgcn_mfma_f32_16x16x32_bf16(afr[rbi][1], b1, a_, 0, 0, 0);
      if (!(l & 15)) *(f32x4*)&gout[gwb + rbi * 16] = a_;
    }
    asm volatile("s_waitcnt lgkmcnt(0)\n\ts_barrier" ::: "memory");
    if (tid < 64) {
      if (i < 64) {
        float r = fsigm(gil[i][tid] + gout[tid] + bR);
        float z = fsigm(gil[i][64 + tid] + gout[64 + tid] + bZ);
        float n = ftanh(gil[i][128 + tid] + r * (gout[128 + tid] + bNa));
        hreg = (1.f - z) * n + z * hreg;
        hv[0][tid] = f2bf(hreg);
      }
    } else if (tid < 128 && i > 0) {
      int g = tid - 64;
      float r = fsigm(gout[192 + g] + gout[384 + g] + bR);
      float z = fsigm(gout[256 + g] + gout[448 + g] + bZ);
      float n = ftanh((gout[320 + g] + bNa) + r * (gout[512 + g] + bNb));
      hreg = (1.f - z) * n + z * hreg;
      hv[1][g] = f2bf(hreg);
      out[(i - 1) * 64 + g] = hreg;
    }
    asm volatile("s_waitcnt lgkmcnt(0)\n\ts_barrier" ::: "memory");
  }
  if (tid < 64) out[4096 + tid] = hreg;
  else if (tid < 128) out[4096 + 64 + (tid - 64)] = hreg;
}

extern "C" void kernel_launch(void* const* d_in, const int* in_sizes, int n_in,
                              void* d_out, int out_size, void* d_ws, size_t ws_size,
                              hipStream_t stream) {
  const float* x    = (const float*)d_in[0];
  const float* adj  = (const float*)d_in[1];
  const float* W1   = (const float*)d_in[2];
  const float* b1   = (const float*)d_in[3];
  const float* W2   = (const float*)d_in[4];
  const float* b2   = (const float*)d_in[5];
  const float* Wih0 = (const float*)d_in[6];
  const float* Whh0 = (const float*)d_in[7];
  const float* bih0 = (const float*)d_in[8];
  const float* bhh0 = (const float*)d_in[9];
  const float* Wih1 = (const float*)d_in[10];
  const float* Whh1 = (const float*)d_in[11];
  const float* bih1 = (const float*)d_in[12];
  const float* bhh1 = (const float*)d_in[13];
  float* out = (float*)d_out;

  char* ws = (char*)d_ws;
  unsigned char* adj8  = (unsigned char*)ws;                       // 16.78MB
  unsigned char* Xt8   = (unsigned char*)(ws + 16777216);          // 8.39MB
  float* rowsum        = (float*)(ws + 25165824);                  // 16KB
  float* Gp            = (float*)(ws + 25182208);                  // 16.78MB
  float* Rm            = (float*)(ws + 41959424);                  // 2MB
  float* part          = (float*)(ws + 44056576);                  // 768KB
  float* gi0           = (float*)(ws + 44843008);                  // 48KB
  unsigned char* B2t8  = (unsigned char*)(ws + 44892160);          // 512KB

  k_prep<<<8192, 256, 0, stream>>>(adj, adj8, rowsum, x, Xt8);
  k_gemmAX<<<256, 512, 0, stream>>>(adj8, Xt8, rowsum, W1, b1, W2, b2, B2t8);
  k_gemm2f8<<<256, 256, 0, stream>>>(adj8, B2t8, Gp);
  k_lsm<<<128, 256, 0, stream>>>(Gp, Rm);
  k_gi0<<<768, 256, 0, stream>>>(Rm, Wih0, part);
  k_gi0red<<<48, 256, 0, stream>>>(part, bih0, gi0);
  k_gru<<<1, 384, 0, stream>>>(gi0, Whh0, bhh0, Wih1, Whh1, bih1, bhh1, out);
}